// Round 1
// baseline (3176.907 us; speedup 1.0000x reference)
//
#include <hip/hip_runtime.h>
#include <hip/hip_bf16.h>
#include <stdint.h>

typedef unsigned short u16;
typedef __bf16 bf16x8 __attribute__((ext_vector_type(8)));
typedef float f32x4 __attribute__((ext_vector_type(4)));

// ---------- helpers ----------
__device__ __forceinline__ u16 f2bf(float f) {
  uint32_t u = __float_as_uint(f);
  u = (u + 0x7FFFu + ((u >> 16) & 1u)) >> 16;  // RNE
  return (u16)u;
}

__device__ __forceinline__ void gl2lds16(const void* g, void* l) {
  __builtin_amdgcn_global_load_lds(
      (const __attribute__((address_space(1))) void*)g,
      (__attribute__((address_space(3))) void*)l, 16, 0, 0);
}

// ---------- f32 -> bf16 array convert (n4 = count/4, exact) ----------
__global__ void cvt_bf16_arr(const float* __restrict__ in, u16* __restrict__ out, int n4) {
  int i = blockIdx.x * blockDim.x + threadIdx.x;
  if (i >= n4) return;
  float4 v = ((const float4*)in)[i];
  ushort4 o;
  o.x = f2bf(v.x); o.y = f2bf(v.y); o.z = f2bf(v.z); o.w = f2bf(v.w);
  ((ushort4*)out)[i] = o;
}

// ---------- pack Whh[j][k] -> u32 {bf16(k),bf16(k+1)} at [k/2][j] ----------
__global__ void pack_whh(const float* __restrict__ W, uint32_t* __restrict__ out) {
  int idx = blockIdx.x * 256 + threadIdx.x;   // 512*256 threads
  int p = idx >> 9, j = idx & 511;
  float a = W[j * 512 + 2 * p];
  float b = W[j * 512 + 2 * p + 1];
  out[p * 512 + j] = (uint32_t)f2bf(a) | ((uint32_t)f2bf(b) << 16);
}

// ---------- gather token embeddings -> bf16 rows (B-major, 128 per batch) ----------
__global__ void gather_embed(const int* __restrict__ tok, const float* __restrict__ embed,
                             u16* __restrict__ out, int tokStride) {
  int m = blockIdx.x;          // 0..4095 : b*128 + pos
  int t = threadIdx.x;         // 128 threads, 4 floats each
  int token = tok[(m >> 7) * tokStride + (m & 127)];
  float4 v = ((const float4*)(embed + (long)token * 512))[t];
  ushort4 o;
  o.x = f2bf(v.x); o.y = f2bf(v.y); o.z = f2bf(v.z); o.w = f2bf(v.w);
  ((ushort4*)(out + (long)m * 512))[t] = o;
}

// ---------- bf16 MFMA GEMM: C[M,N] = A[M,K] * B[N,K]^T (+bias[n]) ----------
// 128x128 tile, BK=32, 4 waves, 16x16x32 MFMA, global_load_lds staging (m97 structure)
__global__ __launch_bounds__(256) void gemm_bf16_kernel(
    const u16* __restrict__ A, const u16* __restrict__ B,
    const float* __restrict__ bias, float* __restrict__ C,
    int M, int N, int K) {
  __shared__ __align__(16) u16 As[4096];
  __shared__ __align__(16) u16 Bs[4096];
  const int tid = threadIdx.x;
  const int lane = tid & 63;
  const int wv = tid >> 6;
  const int wr = wv >> 1, wc = wv & 1;
  const long m0 = (long)blockIdx.y * 128;
  const long n0 = (long)blockIdx.x * 128;

  f32x4 zero = {0.f, 0.f, 0.f, 0.f};
  f32x4 acc[4][4];
#pragma unroll
  for (int i = 0; i < 4; ++i)
#pragma unroll
    for (int j = 0; j < 4; ++j) acc[i][j] = zero;

  const u16* Ag = A + (m0 + (tid >> 2)) * (long)K + (tid & 3) * 8;
  const u16* Bg = B + (n0 + (tid >> 2)) * (long)K + (tid & 3) * 8;
  const u16* Ag2 = Ag + 64 * (long)K;
  const u16* Bg2 = Bg + 64 * (long)K;
  u16* AsW = As + (tid >> 6) * 512;   // wave-uniform LDS base
  u16* BsW = Bs + (tid >> 6) * 512;
  const int ra = (wr * 64 + (lane & 15)) * 32 + (lane >> 4) * 8;
  const int rb = (wc * 64 + (lane & 15)) * 32 + (lane >> 4) * 8;

  for (int kt = 0; kt < K; kt += 32) {
    __syncthreads();                         // previous-tile reads done
    gl2lds16(Ag + kt, AsW);                  // rows 0..63
    gl2lds16(Ag2 + kt, AsW + 2048);          // rows 64..127
    gl2lds16(Bg + kt, BsW);
    gl2lds16(Bg2 + kt, BsW + 2048);
    __syncthreads();                         // vmcnt drained by barrier
    bf16x8 af[4], bfr[4];
#pragma unroll
    for (int i = 0; i < 4; ++i) af[i] = *(const bf16x8*)&As[ra + i * 512];
#pragma unroll
    for (int j = 0; j < 4; ++j) bfr[j] = *(const bf16x8*)&Bs[rb + j * 512];
#pragma unroll
    for (int i = 0; i < 4; ++i)
#pragma unroll
      for (int j = 0; j < 4; ++j)
        acc[i][j] = __builtin_amdgcn_mfma_f32_16x16x32_bf16(af[i], bfr[j], acc[i][j], 0, 0, 0);
  }

#pragma unroll
  for (int i = 0; i < 4; ++i) {
    const long row = m0 + wr * 64 + i * 16 + ((lane >> 4) << 2);
#pragma unroll
    for (int j = 0; j < 4; ++j) {
      const long col = n0 + wc * 64 + j * 16 + (lane & 15);
      const float bv = bias ? bias[col] : 0.f;
#pragma unroll
      for (int r = 0; r < 4; ++r)
        C[(row + r) * (long)N + col] = acc[i][j][r] + bv;
    }
  }
}

// ---------- encoder recurrence: one block per batch, 1024 threads ----------
__global__ __launch_bounds__(1024) void enc_rnn(
    const float* __restrict__ pre, const uint32_t* __restrict__ WhhP,
    const float* __restrict__ bih, const float* __restrict__ bhh,
    float* __restrict__ enc_bsh, u16* __restrict__ enc_bf) {
  const int b = blockIdx.x, tid = threadIdx.x;
  const int j = tid & 511, half = tid >> 9;
  __shared__ float h_sh[512];
  __shared__ float part[2][512];
  if (tid < 512) h_sh[tid] = 0.f;
  const float biasj = bih[j] + bhh[j];
  const uint32_t* wp = WhhP + (long)half * 128 * 512 + j;
  const float2* hp = (const float2*)&h_sh[half * 256];
  __syncthreads();
  for (int t = 0; t < 128; ++t) {
    float a0 = 0.f, a1 = 0.f;
#pragma unroll 8
    for (int kk = 0; kk < 128; kk += 2) {
      uint32_t w0 = wp[(long)kk * 512];
      uint32_t w1 = wp[(long)(kk + 1) * 512];
      float2 h0 = hp[kk];
      float2 h1 = hp[kk + 1];
      a0 += h0.x * __uint_as_float(w0 << 16) + h0.y * __uint_as_float(w0 & 0xFFFF0000u);
      a1 += h1.x * __uint_as_float(w1 << 16) + h1.y * __uint_as_float(w1 & 0xFFFF0000u);
    }
    part[half][j] = a0 + a1;
    __syncthreads();                         // all h_sh reads done
    if (tid < 512) {
      float v = pre[((long)b * 128 + t) * 512 + j] + biasj + part[0][j] + part[1][j];
      float h = tanhf(v);
      h_sh[j] = h;
      enc_bsh[((long)b * 128 + t) * 512 + j] = h;
      enc_bf[((long)b * 128 + t) * 512 + j] = f2bf(h);
    }
    __syncthreads();                         // h_sh update visible
  }
}

// ---------- decoder recurrence + attention: one block per batch, 1024 threads ----------
__global__ __launch_bounds__(1024) void dec_rnn(
    const float* __restrict__ pre, const uint32_t* __restrict__ WhhP,
    const float* __restrict__ bih, const float* __restrict__ bhh,
    const float* __restrict__ enc_t, const float* __restrict__ enc_bsh,
    u16* __restrict__ Hcat, float* __restrict__ att_out) {
  const int b = blockIdx.x, tid = threadIdx.x;
  const int j = tid & 511, half = tid >> 9;
  const int lane = tid & 63, wv = tid >> 6;   // 16 waves
  __shared__ float h_sh[512];
  __shared__ float part[2][512];
  __shared__ float sc_sh[128];
  __shared__ float at_sh[128];
  if (tid < 512) h_sh[tid] = enc_bsh[((long)b * 128 + 127) * 512 + tid];  // h0 = enc last
  const float biasj = bih[j] + bhh[j];
  const uint32_t* wp = WhhP + (long)half * 128 * 512 + j;
  const float2* hp = (const float2*)&h_sh[half * 256];
  const float* et_b = enc_t + (long)b * 128 * 512;
  const float* eb_b = enc_bsh + (long)b * 128 * 512;
  __syncthreads();
  for (int t = 0; t < 128; ++t) {
    // -- 1. h = tanh(pre + Whh @ h + bias)
    float a0 = 0.f, a1 = 0.f;
#pragma unroll 8
    for (int kk = 0; kk < 128; kk += 2) {
      uint32_t w0 = wp[(long)kk * 512];
      uint32_t w1 = wp[(long)(kk + 1) * 512];
      float2 h0 = hp[kk];
      float2 h1 = hp[kk + 1];
      a0 += h0.x * __uint_as_float(w0 << 16) + h0.y * __uint_as_float(w0 & 0xFFFF0000u);
      a1 += h1.x * __uint_as_float(w1 << 16) + h1.y * __uint_as_float(w1 & 0xFFFF0000u);
    }
    part[half][j] = a0 + a1;
    __syncthreads();
    float hreg = 0.f;
    if (tid < 512) {
      float v = pre[((long)b * 128 + t) * 512 + j] + biasj + part[0][j] + part[1][j];
      hreg = tanhf(v);
      h_sh[j] = hreg;
    }
    __syncthreads();
    // -- 2. scores: wave wv handles s = wv*8+q, lane-parallel dot + shfl reduce
#pragma unroll
    for (int q = 0; q < 8; ++q) {
      int s = wv * 8 + q;
      const float* row = et_b + (long)s * 512;
      float a = 0.f;
#pragma unroll
      for (int i = 0; i < 8; ++i) a += h_sh[lane + i * 64] * row[lane + i * 64];
#pragma unroll
      for (int off = 32; off; off >>= 1) a += __shfl_xor(a, off, 64);
      if (lane == 0) sc_sh[s] = a;
    }
    __syncthreads();
    // -- 3. softmax over 128 (wave 0 only, 2 values/lane)
    if (tid < 64) {
      float s0 = sc_sh[tid], s1 = sc_sh[tid + 64];
      float mx = fmaxf(s0, s1);
#pragma unroll
      for (int off = 32; off; off >>= 1) mx = fmaxf(mx, __shfl_xor(mx, off, 64));
      float e0 = __expf(s0 - mx), e1 = __expf(s1 - mx);
      float sm = e0 + e1;
#pragma unroll
      for (int off = 32; off; off >>= 1) sm += __shfl_xor(sm, off, 64);
      float inv = 1.f / sm;
      at_sh[tid] = e0 * inv;
      at_sh[tid + 64] = e1 * inv;
    }
    __syncthreads();
    // -- 4. write attention out: att[b][s][t]
    if (tid < 128) att_out[(long)b * 16384 + (long)tid * 128 + t] = at_sh[tid];
    // -- 5. ctx[j] = sum_s attn[s]*enc_bsh[b][s][j]
    float cacc = 0.f;
#pragma unroll 4
    for (int si = 0; si < 64; ++si) {
      int s = half * 64 + si;
      cacc += at_sh[s] * eb_b[(long)s * 512 + j];
    }
    __syncthreads();                 // part reads from phase 1 are long done; re-use
    part[half][j] = cacc;
    __syncthreads();
    if (tid < 512) {
      float ctx = part[0][j] + part[1][j];
      long r = ((long)b * 128 + t) * 1024;
      Hcat[r + j] = f2bf(hreg);
      Hcat[r + 512 + j] = f2bf(ctx);
    }
    __syncthreads();                 // protect part/sc/at for next step
  }
}

// ---------- launcher ----------
extern "C" void kernel_launch(void* const* d_in, const int* in_sizes, int n_in,
                              void* d_out, int out_size, void* d_ws, size_t ws_size,
                              hipStream_t stream) {
  (void)in_sizes; (void)n_in; (void)out_size; (void)ws_size;
  const int*   source = (const int*)d_in[0];
  const int*   target = (const int*)d_in[1];
  const float* embed  = (const float*)d_in[2];
  const float* encWih = (const float*)d_in[3];
  const float* encWhh = (const float*)d_in[4];
  const float* encBih = (const float*)d_in[5];
  const float* encBhh = (const float*)d_in[6];
  const float* decWih = (const float*)d_in[7];
  const float* decWhh = (const float*)d_in[8];
  const float* decBih = (const float*)d_in[9];
  const float* decBhh = (const float*)d_in[10];
  const float* attnW  = (const float*)d_in[11];
  const float* attnB  = (const float*)d_in[12];
  const float* outW   = (const float*)d_in[13];
  const float* outB   = (const float*)d_in[14];

  float* out_logits = (float*)d_out;
  float* out_att = out_logits + (long)32 * 128 * 32000;

  char* wsb = (char*)d_ws;
  size_t off = 0;
  auto alloc = [&](size_t bytes) {
    char* p = wsb + off;
    off += (bytes + 255) & ~(size_t)255;
    return p;
  };
  u16*      encA   = (u16*)alloc(4096l * 512 * 2);
  u16*      decA   = (u16*)alloc(4096l * 512 * 2);
  u16*      wihE   = (u16*)alloc(512l * 512 * 2);
  u16*      wihD   = (u16*)alloc(512l * 512 * 2);
  u16*      attnWb = (u16*)alloc(512l * 512 * 2);
  uint32_t* whhPe  = (uint32_t*)alloc(256l * 512 * 4);
  uint32_t* whhPd  = (uint32_t*)alloc(256l * 512 * 4);
  u16*      outWb  = (u16*)alloc(32000l * 1024 * 2);
  float*    preE   = (float*)alloc(4096l * 512 * 4);
  float*    preD   = (float*)alloc(4096l * 512 * 4);
  float*    encBsh = (float*)alloc(4096l * 512 * 4);
  u16*      encBf  = (u16*)alloc(4096l * 512 * 2);
  float*    encT   = (float*)alloc(4096l * 512 * 4);
  u16*      hcat   = (u16*)alloc(4096l * 1024 * 2);

  // weight conversions (parallel, independent)
  cvt_bf16_arr<<<256, 256, 0, stream>>>(encWih, wihE, 65536);
  cvt_bf16_arr<<<256, 256, 0, stream>>>(decWih, wihD, 65536);
  cvt_bf16_arr<<<256, 256, 0, stream>>>(attnW, attnWb, 65536);
  cvt_bf16_arr<<<32000, 256, 0, stream>>>(outW, outWb, 8192000);
  pack_whh<<<512, 256, 0, stream>>>(encWhh, whhPe);
  pack_whh<<<512, 256, 0, stream>>>(decWhh, whhPd);
  // embedding gathers
  gather_embed<<<4096, 128, 0, stream>>>(source, embed, encA, 128);
  gather_embed<<<4096, 128, 0, stream>>>(target, embed, decA, 129);
  // pre-activations for all timesteps: x @ Wih^T
  gemm_bf16_kernel<<<dim3(4, 32), 256, 0, stream>>>(encA, wihE, (const float*)nullptr, preE, 4096, 512, 512);
  gemm_bf16_kernel<<<dim3(4, 32), 256, 0, stream>>>(decA, wihD, (const float*)nullptr, preD, 4096, 512, 512);
  // encoder recurrence
  enc_rnn<<<32, 1024, 0, stream>>>(preE, whhPe, encBih, encBhh, encBsh, encBf);
  // enc_t = enc_out @ attn_W^T + attn_b
  gemm_bf16_kernel<<<dim3(4, 32), 256, 0, stream>>>(encBf, attnWb, attnB, encT, 4096, 512, 512);
  // decoder recurrence + attention
  dec_rnn<<<32, 1024, 0, stream>>>(preD, whhPd, decBih, decBhh, encT, encBsh, hcat, out_att);
  // logits = [h,ctx] @ out_W^T + out_b  -> d_out (B,T,C)
  gemm_bf16_kernel<<<dim3(250, 32), 256, 0, stream>>>(hcat, outWb, outB, out_logits, 4096, 32000, 1024);
}